// Round 7
// baseline (102.753 us; speedup 1.0000x reference)
//
#include <hip/hip_runtime.h>

#define P_POSES   32
#define A_ATOMS   4096
#define T_HASH    1048576
#define EPSF      1e-8f
#define KSUB      16          // blocks per pose in k4 (grid = 512)
#define K1G       128         // k1 grid
#define K3T       256
#define K3ITER    8
#define CHUNK     (K3T*K3ITER)   // 2048 items per k3 block

typedef int   int4v   __attribute__((ext_vector_type(4)));
typedef float float4v __attribute__((ext_vector_type(4)));

// ---------------- pass 0: pad hv[T][3] -> hvp[T] (float4, 16B aligned) ----------------
__global__ __launch_bounds__(256) void k0_hvpad(const float* __restrict__ hv,
                                                float4v* __restrict__ hvp) {
    const int stride = gridDim.x * blockDim.x;
    for (int k = blockIdx.x * blockDim.x + threadIdx.x; k < T_HASH; k += stride) {
        float4v v;
        v.x = hv[3*k+0]; v.y = hv[3*k+1]; v.z = hv[3*k+2]; v.w = 0.0f;
        hvp[k] = v;
    }
}

// ---------------- pass 1: per-block pose histograms ----------------
__global__ __launch_bounds__(256) void k1_hist(const int* __restrict__ pose,
                                               int* __restrict__ partials, int S) {
    __shared__ int h[P_POSES];
    if (threadIdx.x < P_POSES) h[threadIdx.x] = 0;
    __syncthreads();
    const int stride = K1G * 256;
    for (int s = blockIdx.x * 256 + threadIdx.x; s < S; s += stride)
        atomicAdd(&h[__builtin_nontemporal_load(&pose[s])], 1);
    __syncthreads();
    if (threadIdx.x < P_POSES) partials[blockIdx.x * P_POSES + threadIdx.x] = h[threadIdx.x];
}

// ---------------- pass 2: reduce+scan, init cursor & out ----------------
__global__ __launch_bounds__(256) void k2_scan(const int* __restrict__ partials,
                                               int* __restrict__ start,
                                               int* __restrict__ cursor,
                                               float* __restrict__ out) {
    __shared__ int sums[256];
    const int tid = threadIdx.x;
    const int bin = tid & 31, grp = tid >> 5;          // 8 groups x 32 bins
    int acc = 0;
    #pragma unroll 4
    for (int b = grp; b < K1G; b += 8) acc += partials[b * P_POSES + bin];
    sums[tid] = acc;
    __syncthreads();
    if (tid < 64) {
        const int lane = tid;
        int c = 0;
        if (lane < P_POSES) {
            #pragma unroll
            for (int g = 0; g < 8; ++g) c += sums[g * 32 + lane];
        }
        int x = c;
        #pragma unroll
        for (int d = 1; d < 32; d <<= 1) {
            int y = __shfl_up(x, d, 64);
            if (lane >= d) x += y;
        }
        if (lane < P_POSES) { start[lane] = x - c; cursor[lane] = x - c; out[lane] = 0.0f; }
        if (lane == 31)     { start[P_POSES] = x; }
    }
}

// ---------------- pass 3: block-local counting sort -> coalesced global writes ----------------
__global__ __launch_bounds__(K3T) void k3_sort(const int*   __restrict__ pose,
                                               const int4v* __restrict__ atoms,
                                               int*   __restrict__ cursor,
                                               int4v* __restrict__ sorted, int S) {
    __shared__ int cnt[P_POSES];
    __shared__ int lstart[P_POSES];
    __shared__ int gbase[P_POSES];
    __shared__ int4v buf[CHUNK];                 // 32 KB
    __shared__ unsigned char posb[CHUNK];        // 2 KB
    const int tid = threadIdx.x;
    if (tid < P_POSES) cnt[tid] = 0;
    __syncthreads();

    const int s0 = blockIdx.x * CHUNK;
    int4v a[K3ITER]; int pp[K3ITER]; int rr[K3ITER]; bool act[K3ITER];

    #pragma unroll
    for (int it = 0; it < K3ITER; ++it) {
        const int s = s0 + it * K3T + tid;
        act[it] = s < S;
        if (act[it]) {
            pp[it] = __builtin_nontemporal_load(&pose[s]);
            a[it]  = __builtin_nontemporal_load(&atoms[s]);
            rr[it] = atomicAdd(&cnt[pp[it]], 1);
        }
    }
    __syncthreads();

    if (tid < 64) {
        const int lane = tid;
        const int c = (lane < P_POSES) ? cnt[lane] : 0;
        int x = c;
        #pragma unroll
        for (int d = 1; d < 32; d <<= 1) {
            int y = __shfl_up(x, d, 64);
            if (lane >= d) x += y;
        }
        if (lane < P_POSES) {
            lstart[lane] = x - c;
            gbase[lane]  = (c > 0) ? atomicAdd(&cursor[lane], c) : 0;
        }
    }
    __syncthreads();

    #pragma unroll
    for (int it = 0; it < K3ITER; ++it) {
        if (act[it]) {
            const int l = lstart[pp[it]] + rr[it];
            buf[l]  = a[it];
            posb[l] = (unsigned char)pp[it];
        }
    }
    __syncthreads();

    const int n = (S - s0 < CHUNK) ? (S - s0) : CHUNK;
    for (int idx = tid; idx < n; idx += K3T) {
        const int p = posb[idx];
        sorted[gbase[p] + (idx - lstart[p])] = buf[idx];
    }
}

// ---------------- pass 4: per-pose scoring, LDS tables, 1-request hv gather ----------------
__global__ __launch_bounds__(256) void k4_main(const float*   __restrict__ coords,
                                               const float*   __restrict__ hv,
                                               const float4v* __restrict__ hvp,
                                               const int      use_hvp,
                                               const int*     __restrict__ uids,
                                               const int*     __restrict__ start,
                                               const int4v*   __restrict__ sorted,
                                               float*         __restrict__ out) {
    __shared__ float sC[A_ATOMS * 3];   // 48 KB
    __shared__ int   sU[A_ATOMS];       // 16 KB

    const int pose = blockIdx.x >> 4;   // KSUB = 16
    const int sub  = blockIdx.x & 15;
    const int tid  = threadIdx.x;

    {   // coalesced staging
        const float4v* src = (const float4v*)(coords + (size_t)pose * (A_ATOMS * 3));
        float4v* dst = (float4v*)sC;
        #pragma unroll 4
        for (int i = tid; i < (A_ATOMS * 3) / 4; i += 256) dst[i] = src[i];
        const int4v* usrc = (const int4v*)(uids + pose * A_ATOMS);
        int4v* udst = (int4v*)sU;
        for (int i = tid; i < A_ATOMS / 4; i += 256) udst[i] = usrc[i];
    }
    __syncthreads();

    const int s0 = start[pose], s1 = start[pose + 1];
    float esum = 0.0f;

    for (int i = s0 + sub * 256 + tid; i < s1; i += KSUB * 256) {
        const int4v a = __builtin_nontemporal_load(&sorted[i]);

        const bool v0 = a.x >= 0, v1 = a.y >= 0, v2 = a.z >= 0, v3 = a.w >= 0;
        const int  i0 = v0 ? a.x : 0;
        const int  i1 = v1 ? a.y : 0;
        const int  i2 = v2 ? a.z : 0;
        const int  i3 = v3 ? a.w : 0;
        const int  nv = (int)v0 + (int)v1 + (int)v2 + (int)v3;

        unsigned int key = 0u;
        key += v0 ? (unsigned int)sU[i0] : 0u;
        key += v1 ? (unsigned int)sU[i1] : 0u;
        key += v2 ? (unsigned int)sU[i2] : 0u;
        key += v3 ? (unsigned int)sU[i3] : 0u;
        key &= (unsigned int)(T_HASH - 1);

        float K, x0, period;
        if (use_hvp) {
            const float4v H = hvp[key];          // single 16B aligned gather
            K = H.x; x0 = H.y; period = H.z;
        } else {
            K      = hv[3 * (size_t)key + 0];
            x0     = hv[3 * (size_t)key + 1];
            period = hv[3 * (size_t)key + 2];
        }

        const float p0x = sC[3*i0+0], p0y = sC[3*i0+1], p0z = sC[3*i0+2];
        const float p1x = sC[3*i1+0], p1y = sC[3*i1+1], p1z = sC[3*i1+2];
        const float p2x = sC[3*i2+0], p2y = sC[3*i2+1], p2z = sC[3*i2+2];
        const float p3x = sC[3*i3+0], p3y = sC[3*i3+1], p3z = sC[3*i3+2];

        // bond
        const float dbx = p1x - p0x, dby = p1y - p0y, dbz = p1z - p0z;
        const float d  = sqrtf(dbx*dbx + dby*dby + dbz*dbz + EPSF);
        const float db = d - x0;
        const float e_bond = K * db * db;

        // angle (u = p0-p1, v = p2-p1)
        const float ux = -dbx, uy = -dby, uz = -dbz;
        const float vx = p2x - p1x, vy = p2y - p1y, vz = p2z - p1z;
        const float uv = ux*vx + uy*vy + uz*vz;
        const float uu = ux*ux + uy*uy + uz*uz;
        const float vv = vx*vx + vy*vy + vz*vz;
        float cosang = uv / (sqrtf(uu + EPSF) * sqrtf(vv + EPSF));
        cosang = fminf(fmaxf(cosang, -0.999999f), 0.999999f);
        const float theta = acosf(cosang);
        const float da = theta - x0;
        const float e_angle = K * da * da;

        // torsion
        const float b2x = vx,  b2y = vy,  b2z = vz;
        const float b3x = p3x - p2x, b3y = p3y - p2y, b3z = p3z - p2z;
        const float n1x = dby*b2z - dbz*b2y;
        const float n1y = dbz*b2x - dbx*b2z;
        const float n1z = dbx*b2y - dby*b2x;
        const float n2x = b2y*b3z - b2z*b3y;
        const float n2y = b2z*b3x - b2x*b3z;
        const float n2z = b2x*b3y - b2y*b3x;
        const float b2inv = 1.0f / sqrtf(b2x*b2x + b2y*b2y + b2z*b2z + EPSF);
        const float bnx = b2x*b2inv, bny = b2y*b2inv, bnz = b2z*b2inv;
        const float m1x = n1y*bnz - n1z*bny;
        const float m1y = n1z*bnx - n1x*bnz;
        const float m1z = n1x*bny - n1y*bnx;
        const float sy = m1x*n2x + m1y*n2y + m1z*n2z;
        const float sx = n1x*n2x + n1y*n2y + n1z*n2z + EPSF;
        const float phi = atan2f(sy, sx);
        const float e_tors = K * (1.0f + cosf(period*phi - x0));

        esum += (nv == 2) ? e_bond : ((nv == 3) ? e_angle : e_tors);
    }

    #pragma unroll
    for (int off = 32; off > 0; off >>= 1) esum += __shfl_down(esum, off, 64);
    if ((tid & 63) == 0 && esum != 0.0f) atomicAdd(&out[pose], esum);
}

// ---------------- fallback (proven monolithic path) ----------------
__global__ __launch_bounds__(256) void fb_kernel(const float* __restrict__ coords,
                                                 const float* __restrict__ hv,
                                                 const int4v* __restrict__ atoms,
                                                 const int*   __restrict__ pose,
                                                 const int*   __restrict__ uids,
                                                 float* __restrict__ out, int S) {
    __shared__ float bins[P_POSES];
    if (threadIdx.x < P_POSES) bins[threadIdx.x] = 0.0f;
    __syncthreads();
    const int s = blockIdx.x * blockDim.x + threadIdx.x;
    if (s < S) {
        const int4v a = atoms[s];
        const int   p = pose[s];
        const bool v0 = a.x >= 0, v1 = a.y >= 0, v2 = a.z >= 0, v3 = a.w >= 0;
        const int  i0 = v0 ? a.x : 0, i1 = v1 ? a.y : 0, i2 = v2 ? a.z : 0, i3 = v3 ? a.w : 0;
        const int  nv = (int)v0 + (int)v1 + (int)v2 + (int)v3;
        const int* urow = uids + p * A_ATOMS;
        unsigned int key = (v0?(unsigned)urow[i0]:0u) + (v1?(unsigned)urow[i1]:0u)
                         + (v2?(unsigned)urow[i2]:0u) + (v3?(unsigned)urow[i3]:0u);
        key &= (unsigned)(T_HASH - 1);
        const float K = hv[3*key], x0 = hv[3*key+1], period = hv[3*key+2];
        const float* crow = coords + (size_t)p * (A_ATOMS * 3);
        const float p0x=crow[i0*3],p0y=crow[i0*3+1],p0z=crow[i0*3+2];
        const float p1x=crow[i1*3],p1y=crow[i1*3+1],p1z=crow[i1*3+2];
        const float p2x=crow[i2*3],p2y=crow[i2*3+1],p2z=crow[i2*3+2];
        const float p3x=crow[i3*3],p3y=crow[i3*3+1],p3z=crow[i3*3+2];
        const float dbx=p1x-p0x,dby=p1y-p0y,dbz=p1z-p0z;
        const float d=sqrtf(dbx*dbx+dby*dby+dbz*dbz+EPSF);
        const float e_bond=K*(d-x0)*(d-x0);
        const float ux=-dbx,uy=-dby,uz=-dbz;
        const float vx=p2x-p1x,vy=p2y-p1y,vz=p2z-p1z;
        float cosang=(ux*vx+uy*vy+uz*vz)/(sqrtf(ux*ux+uy*uy+uz*uz+EPSF)*sqrtf(vx*vx+vy*vy+vz*vz+EPSF));
        cosang=fminf(fmaxf(cosang,-0.999999f),0.999999f);
        const float th=acosf(cosang);
        const float e_angle=K*(th-x0)*(th-x0);
        const float b3x=p3x-p2x,b3y=p3y-p2y,b3z=p3z-p2z;
        const float n1x=dby*vz-dbz*vy,n1y=dbz*vx-dbx*vz,n1z=dbx*vy-dby*vx;
        const float n2x=vy*b3z-vz*b3y,n2y=vz*b3x-vx*b3z,n2z=vx*b3y-vy*b3x;
        const float bi=1.0f/sqrtf(vx*vx+vy*vy+vz*vz+EPSF);
        const float bnx=vx*bi,bny=vy*bi,bnz=vz*bi;
        const float m1x=n1y*bnz-n1z*bny,m1y=n1z*bnx-n1x*bnz,m1z=n1x*bny-n1y*bnx;
        const float sy=m1x*n2x+m1y*n2y+m1z*n2z;
        const float sx=n1x*n2x+n1y*n2y+n1z*n2z+EPSF;
        const float e_tors=K*(1.0f+cosf(period*atan2f(sy,sx)-x0));
        atomicAdd(&bins[p],(nv==2)?e_bond:((nv==3)?e_angle:e_tors));
    }
    __syncthreads();
    if (threadIdx.x < P_POSES) {
        const float b = bins[threadIdx.x];
        if (b != 0.0f) atomicAdd(&out[threadIdx.x], b);
    }
}

extern "C" void kernel_launch(void* const* d_in, const int* in_sizes, int n_in,
                              void* d_out, int out_size, void* d_ws, size_t ws_size,
                              hipStream_t stream) {
    const float* coords = (const float*)d_in[0];
    const float* hv     = (const float*)d_in[1];
    const int4v* atoms  = (const int4v*)d_in[2];
    const int*   pose   = (const int*)d_in[3];
    const int*   uids   = (const int*)d_in[4];
    float* out = (float*)d_out;
    const int S = in_sizes[3];

    // ws layout: partials[K1G*32] | start[33]+cursor[32] | sorted[S] | hvp[T]
    const size_t off_meta   = (size_t)K1G * P_POSES * 4;   // 16 KB
    const size_t off_sorted = off_meta + 1024;
    const size_t off_hvp    = off_sorted + (size_t)S * 16;
    const size_t mid_need   = off_hvp;
    const size_t full_need  = off_hvp + (size_t)T_HASH * 16;

    if (ws_size < mid_need) {
        hipMemsetAsync(out, 0, P_POSES * sizeof(float), stream);
        fb_kernel<<<(S + 255) / 256, 256, 0, stream>>>(coords, hv, atoms, pose, uids, out, S);
        return;
    }

    int*     partials = (int*)d_ws;
    int*     start    = (int*)((char*)d_ws + off_meta);
    int*     cursor   = start + 64;
    int4v*   sorted   = (int4v*)((char*)d_ws + off_sorted);
    float4v* hvp      = (float4v*)((char*)d_ws + off_hvp);
    const int use_hvp = (ws_size >= full_need) ? 1 : 0;

    if (use_hvp) k0_hvpad<<<1024, 256, 0, stream>>>(hv, hvp);
    k1_hist<<<K1G, 256, 0, stream>>>(pose, partials, S);
    k2_scan<<<1, 256, 0, stream>>>(partials, start, cursor, out);
    k3_sort<<<(S + CHUNK - 1) / CHUNK, K3T, 0, stream>>>(pose, atoms, cursor, sorted, S);
    k4_main<<<P_POSES * KSUB, 256, 0, stream>>>(coords, hv, hvp, use_hvp, uids, start, sorted, out);
}

// Round 8
// 83.473 us; speedup vs baseline: 1.2310x; 1.2310x over previous
//
#include <hip/hip_runtime.h>

#define P_POSES   32
#define A_ATOMS   4096
#define T_HASH    1048576
#define EPSF      1e-8f
#define NBKT      256          // 32 poses x 8 key slices
#define KS        3            // sub-blocks per bucket in kB (grid = 768)
#define CHUNK     2048         // items per kA block

typedef int   int4v   __attribute__((ext_vector_type(4)));
typedef float float4v __attribute__((ext_vector_type(4)));

// ---------------- init: bucket cursors + output ----------------
__global__ __launch_bounds__(256) void k_init(int* __restrict__ cursor,
                                              float* __restrict__ out, int cap) {
    const int t = threadIdx.x;
    cursor[t] = t * cap;
    if (t < P_POSES) out[t] = 0.0f;
}

// ---------------- kA: compute key, pack record, bucket by (pose, key>>17) ----------------
__global__ __launch_bounds__(256) void kA_bucket(const int4v* __restrict__ atoms,
                                                 const int*   __restrict__ pose,
                                                 const int*   __restrict__ uids,
                                                 int*         __restrict__ cursor,
                                                 int4v*       __restrict__ rec,
                                                 int S, int cap) {
    __shared__ int4v buf[CHUNK];                // 32 KB
    __shared__ unsigned char bkt[CHUNK];        // 2 KB
    __shared__ int cnt[NBKT];
    __shared__ int lstart[NBKT];
    __shared__ int gbase[NBKT];
    __shared__ int wsum[4];

    const int tid  = threadIdx.x;
    const int lane = tid & 63;
    cnt[tid] = 0;
    __syncthreads();

    const int s0 = blockIdx.x * CHUNK;
    int4v pk[8]; int bb[8], rr[8]; bool act[8];

    #pragma unroll
    for (int it = 0; it < 8; ++it) {
        const int s = s0 + it * 256 + tid;
        act[it] = s < S;
        if (act[it]) {
            const int4v a = __builtin_nontemporal_load(&atoms[s]);
            const int   p = __builtin_nontemporal_load(&pose[s]);
            const bool v0 = a.x >= 0, v1 = a.y >= 0, v2 = a.z >= 0, v3 = a.w >= 0;
            const int  i0 = v0 ? a.x : 0;
            const int  i1 = v1 ? a.y : 0;
            const int  i2 = v2 ? a.z : 0;
            const int  i3 = v3 ? a.w : 0;
            const int  nv = (int)v0 + (int)v1 + (int)v2 + (int)v3;
            const int* __restrict__ urow = uids + p * A_ATOMS;
            unsigned int key = (v0 ? (unsigned)urow[i0] : 0u)
                             + (v1 ? (unsigned)urow[i1] : 0u)
                             + (v2 ? (unsigned)urow[i2] : 0u)
                             + (v3 ? (unsigned)urow[i3] : 0u);
            key &= (unsigned)(T_HASH - 1);
            const int b = (p << 3) | (int)(key >> 17);
            int4v r;
            r.x = i0 | (i1 << 16);
            r.y = i2 | (i3 << 16);
            r.z = (int)(key | ((unsigned)nv << 20) | ((unsigned)p << 23));
            r.w = 0;
            pk[it] = r; bb[it] = b;
            rr[it] = atomicAdd(&cnt[b], 1);
        }
    }
    __syncthreads();

    // 256-bin exclusive scan (4 waves) + global base reservation
    {
        const int c = cnt[tid];
        int x = c;
        #pragma unroll
        for (int d = 1; d < 64; d <<= 1) {
            int y = __shfl_up(x, d, 64);
            if (lane >= d) x += y;
        }
        if (lane == 63) wsum[tid >> 6] = x;
        __syncthreads();
        int off = 0;
        const int w = tid >> 6;
        for (int g = 0; g < w; ++g) off += wsum[g];
        lstart[tid] = x - c + off;
        gbase[tid]  = (c > 0) ? atomicAdd(&cursor[tid], c) : 0;
    }
    __syncthreads();

    #pragma unroll
    for (int it = 0; it < 8; ++it) {
        if (act[it]) {
            const int l = lstart[bb[it]] + rr[it];
            buf[l] = pk[it];
            bkt[l] = (unsigned char)bb[it];
        }
    }
    __syncthreads();

    const int n = (S - s0 < CHUNK) ? (S - s0) : CHUNK;
    for (int idx = tid; idx < n; idx += 256) {
        const int b = bkt[idx];
        rec[(size_t)gbase[b] + (idx - lstart[b])] = buf[idx];
    }
}

// ---------------- kB: per-(pose,slice) scoring; coords in LDS, hv slice L2-local ----------------
__global__ __launch_bounds__(256) void kB_score(const float* __restrict__ coords,
                                                const float* __restrict__ hv,
                                                const int*   __restrict__ cursor,
                                                const int4v* __restrict__ rec,
                                                float*       __restrict__ out, int cap) {
    __shared__ float sC[A_ATOMS * 3];   // 48 KB

    const int blk   = blockIdx.x;
    const int pose  = (blk >> 3) & 31;
    const int ks    = blk >> 8;               // 0..KS-1
    const int b     = blk & 255;              // (pose<<3)|slice
    const int tid   = threadIdx.x;

    {   // stage this pose's coords (coalesced float4)
        const float4v* src = (const float4v*)(coords + (size_t)pose * (A_ATOMS * 3));
        float4v* dst = (float4v*)sC;
        #pragma unroll 4
        for (int i = tid; i < (A_ATOMS * 3) / 4; i += 256) dst[i] = src[i];
    }
    __syncthreads();

    const int base = b * cap;
    const int end  = cursor[b];               // absolute end of bucket
    float esum = 0.0f;

    for (int i = base + ks * 256 + tid; i < end; i += KS * 256) {
        const int4v r = rec[i];
        const int i0 = r.x & 0xFFFF;
        const int i1 = ((unsigned)r.x) >> 16;
        const int i2 = r.y & 0xFFFF;
        const int i3 = ((unsigned)r.y) >> 16;
        const unsigned rz = (unsigned)r.z;
        const unsigned key = rz & (unsigned)(T_HASH - 1);
        const int nv = (int)((rz >> 20) & 7u);

        const float K      = hv[3 * (size_t)key + 0];
        const float x0     = hv[3 * (size_t)key + 1];
        const float period = hv[3 * (size_t)key + 2];

        const float p0x = sC[3*i0+0], p0y = sC[3*i0+1], p0z = sC[3*i0+2];
        const float p1x = sC[3*i1+0], p1y = sC[3*i1+1], p1z = sC[3*i1+2];
        const float p2x = sC[3*i2+0], p2y = sC[3*i2+1], p2z = sC[3*i2+2];
        const float p3x = sC[3*i3+0], p3y = sC[3*i3+1], p3z = sC[3*i3+2];

        // bond
        const float dbx = p1x - p0x, dby = p1y - p0y, dbz = p1z - p0z;
        const float d  = sqrtf(dbx*dbx + dby*dby + dbz*dbz + EPSF);
        const float db = d - x0;
        const float e_bond = K * db * db;

        // angle (u = p0-p1, v = p2-p1)
        const float ux = -dbx, uy = -dby, uz = -dbz;
        const float vx = p2x - p1x, vy = p2y - p1y, vz = p2z - p1z;
        const float uv = ux*vx + uy*vy + uz*vz;
        const float uu = ux*ux + uy*uy + uz*uz;
        const float vv = vx*vx + vy*vy + vz*vz;
        float cosang = uv / (sqrtf(uu + EPSF) * sqrtf(vv + EPSF));
        cosang = fminf(fmaxf(cosang, -0.999999f), 0.999999f);
        const float theta = acosf(cosang);
        const float da = theta - x0;
        const float e_angle = K * da * da;

        // torsion
        const float b2x = vx,  b2y = vy,  b2z = vz;
        const float b3x = p3x - p2x, b3y = p3y - p2y, b3z = p3z - p2z;
        const float n1x = dby*b2z - dbz*b2y;
        const float n1y = dbz*b2x - dbx*b2z;
        const float n1z = dbx*b2y - dby*b2x;
        const float n2x = b2y*b3z - b2z*b3y;
        const float n2y = b2z*b3x - b2x*b3z;
        const float n2z = b2x*b3y - b2y*b3x;
        const float b2inv = 1.0f / sqrtf(b2x*b2x + b2y*b2y + b2z*b2z + EPSF);
        const float bnx = b2x*b2inv, bny = b2y*b2inv, bnz = b2z*b2inv;
        const float m1x = n1y*bnz - n1z*bny;
        const float m1y = n1z*bnx - n1x*bnz;
        const float m1z = n1x*bny - n1y*bnx;
        const float sy = m1x*n2x + m1y*n2y + m1z*n2z;
        const float sx = n1x*n2x + n1y*n2y + n1z*n2z + EPSF;
        const float phi = atan2f(sy, sx);
        const float e_tors = K * (1.0f + cosf(period*phi - x0));

        esum += (nv == 2) ? e_bond : ((nv == 3) ? e_angle : e_tors);
    }

    #pragma unroll
    for (int off = 32; off > 0; off >>= 1) esum += __shfl_down(esum, off, 64);
    if ((tid & 63) == 0 && esum != 0.0f) atomicAdd(&out[pose], esum);
}

// ---------------- fallback (proven monolithic path) ----------------
__global__ __launch_bounds__(256) void fb_kernel(const float* __restrict__ coords,
                                                 const float* __restrict__ hv,
                                                 const int4v* __restrict__ atoms,
                                                 const int*   __restrict__ pose,
                                                 const int*   __restrict__ uids,
                                                 float* __restrict__ out, int S) {
    __shared__ float bins[P_POSES];
    if (threadIdx.x < P_POSES) bins[threadIdx.x] = 0.0f;
    __syncthreads();
    const int s = blockIdx.x * blockDim.x + threadIdx.x;
    if (s < S) {
        const int4v a = atoms[s];
        const int   p = pose[s];
        const bool v0 = a.x >= 0, v1 = a.y >= 0, v2 = a.z >= 0, v3 = a.w >= 0;
        const int  i0 = v0 ? a.x : 0, i1 = v1 ? a.y : 0, i2 = v2 ? a.z : 0, i3 = v3 ? a.w : 0;
        const int  nv = (int)v0 + (int)v1 + (int)v2 + (int)v3;
        const int* urow = uids + p * A_ATOMS;
        unsigned int key = (v0?(unsigned)urow[i0]:0u) + (v1?(unsigned)urow[i1]:0u)
                         + (v2?(unsigned)urow[i2]:0u) + (v3?(unsigned)urow[i3]:0u);
        key &= (unsigned)(T_HASH - 1);
        const float K = hv[3*key], x0 = hv[3*key+1], period = hv[3*key+2];
        const float* crow = coords + (size_t)p * (A_ATOMS * 3);
        const float p0x=crow[i0*3],p0y=crow[i0*3+1],p0z=crow[i0*3+2];
        const float p1x=crow[i1*3],p1y=crow[i1*3+1],p1z=crow[i1*3+2];
        const float p2x=crow[i2*3],p2y=crow[i2*3+1],p2z=crow[i2*3+2];
        const float p3x=crow[i3*3],p3y=crow[i3*3+1],p3z=crow[i3*3+2];
        const float dbx=p1x-p0x,dby=p1y-p0y,dbz=p1z-p0z;
        const float d=sqrtf(dbx*dbx+dby*dby+dbz*dbz+EPSF);
        const float e_bond=K*(d-x0)*(d-x0);
        const float ux=-dbx,uy=-dby,uz=-dbz;
        const float vx=p2x-p1x,vy=p2y-p1y,vz=p2z-p1z;
        float cosang=(ux*vx+uy*vy+uz*vz)/(sqrtf(ux*ux+uy*uy+uz*uz+EPSF)*sqrtf(vx*vx+vy*vy+vz*vz+EPSF));
        cosang=fminf(fmaxf(cosang,-0.999999f),0.999999f);
        const float th=acosf(cosang);
        const float e_angle=K*(th-x0)*(th-x0);
        const float b3x=p3x-p2x,b3y=p3y-p2y,b3z=p3z-p2z;
        const float n1x=dby*vz-dbz*vy,n1y=dbz*vx-dbx*vz,n1z=dbx*vy-dby*vx;
        const float n2x=vy*b3z-vz*b3y,n2y=vz*b3x-vx*b3z,n2z=vx*b3y-vy*b3x;
        const float bi=1.0f/sqrtf(vx*vx+vy*vy+vz*vz+EPSF);
        const float bnx=vx*bi,bny=vy*bi,bnz=vz*bi;
        const float m1x=n1y*bnz-n1z*bny,m1y=n1z*bnx-n1x*bnz,m1z=n1x*bny-n1y*bnx;
        const float sy=m1x*n2x+m1y*n2y+m1z*n2z;
        const float sx=n1x*n2x+n1y*n2y+n1z*n2z+EPSF;
        const float e_tors=K*(1.0f+cosf(period*atan2f(sy,sx)-x0));
        atomicAdd(&bins[p],(nv==2)?e_bond:((nv==3)?e_angle:e_tors));
    }
    __syncthreads();
    if (threadIdx.x < P_POSES) {
        const float b = bins[threadIdx.x];
        if (b != 0.0f) atomicAdd(&out[threadIdx.x], b);
    }
}

extern "C" void kernel_launch(void* const* d_in, const int* in_sizes, int n_in,
                              void* d_out, int out_size, void* d_ws, size_t ws_size,
                              hipStream_t stream) {
    const float* coords = (const float*)d_in[0];
    const float* hv     = (const float*)d_in[1];
    const int4v* atoms  = (const int4v*)d_in[2];
    const int*   pose   = (const int*)d_in[3];
    const int*   uids   = (const int*)d_in[4];
    float* out = (float*)d_out;
    const int S = in_sizes[3];

    // bucket capacity: 1.4x the mean bucket size (mean +30 sigma for multinomial spread)
    int cap = (int)(((long long)S / NBKT) * 7 / 5);
    cap = (cap + 63) & ~63;

    // ws layout: cursor[256] (4KB pad) | rec[NBKT*cap]
    const size_t need = 4096 + (size_t)NBKT * cap * 16;

    if (ws_size < need) {
        hipMemsetAsync(out, 0, P_POSES * sizeof(float), stream);
        fb_kernel<<<(S + 255) / 256, 256, 0, stream>>>(coords, hv, atoms, pose, uids, out, S);
        return;
    }

    int*   cursor = (int*)d_ws;
    int4v* rec    = (int4v*)((char*)d_ws + 4096);

    k_init<<<1, 256, 0, stream>>>(cursor, out, cap);
    kA_bucket<<<(S + CHUNK - 1) / CHUNK, 256, 0, stream>>>(atoms, pose, uids, cursor, rec, S, cap);
    kB_score<<<NBKT * KS, 256, 0, stream>>>(coords, hv, cursor, rec, out, cap);
}